// Round 1
// baseline (521.437 us; speedup 1.0000x reference)
//
#include <hip/hip_runtime.h>

// Equivariant linear: irreps [(32,1),(16,3),(8,5),(4,7)], DIM=148.
// out[n, off_b + v*d + i] = mul^-0.5 * sum_u x[n, off_b + u*d + i] * w_b[u*mul + v]
//
// Memory-bound (AI ~3.8 FLOP/B). Strategy: 64-row tiles staged to LDS via
// global_load_lds (coalesced), per-lane row compute with scalar-loaded
// weights, coalesced flush through LDS.

#define ROWF   148          // floats per row
#define ROWF4  37           // float4 per row
#define ROWS   64           // rows per wave-tile
#define TILE_F4 (ROWS * ROWF4)  // 2368

typedef const __attribute__((address_space(1))) void* gptr_t;
typedef __attribute__((address_space(3))) void* lptr_t;

template <int MUL, int D, int OFF>
__device__ __forceinline__ void proc_block(float* __restrict__ row,
                                           const float* __restrict__ w,
                                           float scale) {
    constexpr int SZ  = MUL * D;
    constexpr int NF4 = SZ / 4;
    float4* row4 = (float4*)(row + OFF);  // OFF divisible by 4, row 16B-aligned

    float x[SZ];
#pragma unroll
    for (int j = 0; j < NF4; ++j) {
        float4 v = row4[j];
        x[4 * j + 0] = v.x;
        x[4 * j + 1] = v.y;
        x[4 * j + 2] = v.z;
        x[4 * j + 3] = v.w;
    }

    float acc[SZ];
#pragma unroll
    for (int k = 0; k < SZ; ++k) acc[k] = 0.0f;

#pragma unroll
    for (int u = 0; u < MUL; ++u) {
#pragma unroll
        for (int v = 0; v < MUL; ++v) {
            // w is a kernel arg with constexpr index -> uniform -> s_load
            float wv = w[u * MUL + v];
#pragma unroll
            for (int i = 0; i < D; ++i) {
                acc[v * D + i] += x[u * D + i] * wv;
            }
        }
    }

#pragma unroll
    for (int j = 0; j < NF4; ++j) {
        float4 o;
        o.x = acc[4 * j + 0] * scale;
        o.y = acc[4 * j + 1] * scale;
        o.z = acc[4 * j + 2] * scale;
        o.w = acc[4 * j + 3] * scale;
        row4[j] = o;  // overwrite x-block with out-block (same lane's row)
    }
}

__global__ __launch_bounds__(64) void eqlin_kernel(
    const float* __restrict__ x,
    const float* __restrict__ w0,
    const float* __restrict__ w1,
    const float* __restrict__ w2,
    const float* __restrict__ w3,
    float* __restrict__ out) {
    __shared__ float lds[ROWS * ROWF];  // 37888 B

    const int lane = threadIdx.x;                    // 0..63, one wave per WG
    const size_t base_f4 = (size_t)blockIdx.x * TILE_F4;

    // ---- Stage: global -> LDS, flat coalesced copy, 37 x width-16 DMA ----
    {
        const float4* src = (const float4*)x + base_f4 + lane;
#pragma unroll
        for (int j = 0; j < ROWF4; ++j) {
            __builtin_amdgcn_global_load_lds(
                (gptr_t)(src + j * 64),
                (lptr_t)(lds + j * 256 + lane * 4),  // uniform base + lane*16B
                16, 0, 0);
        }
    }
    __syncthreads();  // drains vmcnt(0) -> LDS tile visible

    // ---- Compute: lane owns row `lane` of the tile ----
    {
        float* row = lds + lane * ROWF;  // 592 B stride, 16B aligned
        proc_block<32, 1, 0>(row, w0, 0.17677669529663687f);   // 32^-0.5
        proc_block<16, 3, 32>(row, w1, 0.25f);                 // 16^-0.5
        proc_block<8, 5, 80>(row, w2, 0.35355339059327373f);   //  8^-0.5
        proc_block<4, 7, 120>(row, w3, 0.5f);                  //  4^-0.5
    }
    __syncthreads();  // single wave: cheap; orders ds_writes vs flush reads

    // ---- Flush: LDS -> global, flat coalesced copy ----
    {
        const float4* lds4 = (const float4*)lds;
        float4* dst = (float4*)out + base_f4 + lane;
#pragma unroll
        for (int j = 0; j < ROWF4; ++j) {
            dst[j * 64] = lds4[j * 64 + lane];
        }
    }
}

extern "C" void kernel_launch(void* const* d_in, const int* in_sizes, int n_in,
                              void* d_out, int out_size, void* d_ws, size_t ws_size,
                              hipStream_t stream) {
    const float* x  = (const float*)d_in[0];
    const float* w0 = (const float*)d_in[1];
    const float* w1 = (const float*)d_in[2];
    const float* w2 = (const float*)d_in[3];
    const float* w3 = (const float*)d_in[4];
    float* out = (float*)d_out;

    const int N = in_sizes[0] / ROWF;      // 524288
    const int tiles = N / ROWS;            // 8192 (exact)

    eqlin_kernel<<<dim3(tiles), dim3(64), 0, stream>>>(x, w0, w1, w2, w3, out);
}